// Round 1
// baseline (272.521 us; speedup 1.0000x reference)
//
#include <hip/hip_runtime.h>

// SlotAttention on MI355X (gfx950).
// Pipeline: f32->bf16 convert (s, d, Wq, Wk, Wv) -> three bf16 MFMA GEMMs
// (Q=s@Wq^T+bq, K=d@Wk^T+bk, V=d@Wv^T+bv) -> fused slot-attention kernel
// (scores, softmax over slots, PV with ones-column for n) -> reduce/normalize.

#define TS 64
#define TD 4096
#define BATCH 8
#define HC 1024
#define NHEAD 16
#define MD (TD*BATCH)   // 32768
#define MS (TS*BATCH)   // 512
#define NCHUNK 8
#define CHTOK (TD/NCHUNK) // 512

typedef __attribute__((ext_vector_type(8))) __bf16 bf16x8;
typedef __attribute__((ext_vector_type(4))) float f32x4;
typedef __attribute__((ext_vector_type(4))) unsigned short u16x4;
typedef __attribute__((ext_vector_type(8))) unsigned short u16x8;

__device__ __forceinline__ unsigned short f2bf(float x){
  union { float f; unsigned u; } v; v.f = x;
  unsigned r = v.u + 0x7FFFu + ((v.u >> 16) & 1u);
  return (unsigned short)(r >> 16);
}

__device__ __forceinline__ void gll16(const void* g, void* l){
  __builtin_amdgcn_global_load_lds((__attribute__((address_space(1))) void*)g,
                                   (__attribute__((address_space(3))) void*)l, 16, 0, 0);
}

__global__ void cvt_bf16(const float* __restrict__ in, unsigned short* __restrict__ out, int n4){
  int i = blockIdx.x * blockDim.x + threadIdx.x;
  if (i >= n4) return;
  f32x4 f = ((const f32x4*)in)[i];
  u16x4 o;
  o[0] = f2bf(f[0]); o[1] = f2bf(f[1]); o[2] = f2bf(f[2]); o[3] = f2bf(f[3]);
  ((u16x4*)out)[i] = o;
}

// C[M x 1024] = A[M x 1024] @ W^T + bias, all bf16 except bias f32, C bf16.
// 128x128 tile, BK=64, 4 waves (2x2), global_load_lds with pre-swizzled source.
__global__ __launch_bounds__(256) void gemm128(
    const unsigned short* __restrict__ A,
    const unsigned short* __restrict__ W,
    const float* __restrict__ bias,
    unsigned short* __restrict__ C)
{
  __shared__ unsigned short As[128*64];
  __shared__ unsigned short Bs[128*64];
  const int nwg = gridDim.x;
  const int cpx = nwg >> 3;               // nwg % 8 == 0 always here
  const int orig = blockIdx.x;
  const int wg = (orig & 7) * cpx + (orig >> 3);   // bijective XCD swizzle
  const int mt = wg >> 3, nt = wg & 7;
  const int tid = threadIdx.x;
  const int lane = tid & 63, w = tid >> 6;
  const int l15 = lane & 15, lg = lane >> 4;
  const int wr = w >> 1, wc = w & 1;

  // staging: wave w stages rows [w*32, w*32+32) of both tiles, 4 x 1KB instrs each
  const int lrow = lane >> 3;             // 0..7
  const int lch  = (lane & 7) << 4;       // byte chunk 0..112
  const char* pA[4]; const char* pB[4]; unsigned ldsoff[4];
  #pragma unroll
  for (int j = 0; j < 4; ++j){
    int row = w*32 + j*8 + lrow;
    int sw  = lch ^ ((row & 7) << 4);     // pre-swizzled global source (m173 pattern)
    pA[j] = (const char*)A + (size_t)(mt*128 + row) * 2048 + sw;
    pB[j] = (const char*)W + (size_t)(nt*128 + row) * 2048 + sw;
    ldsoff[j] = (unsigned)(w*32 + j*8) * 128;
  }

  const f32x4 fz = {0.f, 0.f, 0.f, 0.f};
  f32x4 acc[4][4];
  #pragma unroll
  for (int m = 0; m < 4; ++m)
    #pragma unroll
    for (int n = 0; n < 4; ++n) acc[m][n] = fz;

  for (int kt = 0; kt < 16; ++kt){
    __syncthreads();
    #pragma unroll
    for (int j = 0; j < 4; ++j){
      gll16(pA[j] + (size_t)kt*128, (char*)As + ldsoff[j]);
      gll16(pB[j] + (size_t)kt*128, (char*)Bs + ldsoff[j]);
    }
    __syncthreads();   // drains vmcnt -> LDS tiles ready
    #pragma unroll
    for (int kk = 0; kk < 2; ++kk){
      bf16x8 af[4], bfr[4];
      #pragma unroll
      for (int m = 0; m < 4; ++m){
        int row = wr*64 + m*16 + l15;
        af[m] = *(const bf16x8*)((const char*)As + row*128 + ((lg*16 + kk*64) ^ ((row & 7) << 4)));
      }
      #pragma unroll
      for (int n = 0; n < 4; ++n){
        int row = wc*64 + n*16 + l15;
        bfr[n] = *(const bf16x8*)((const char*)Bs + row*128 + ((lg*16 + kk*64) ^ ((row & 7) << 4)));
      }
      #pragma unroll
      for (int m = 0; m < 4; ++m)
        #pragma unroll
        for (int n = 0; n < 4; ++n)
          acc[m][n] = __builtin_amdgcn_mfma_f32_16x16x32_bf16(af[m], bfr[n], acc[m][n], 0, 0, 0);
    }
  }

  const int ccol0 = nt*128 + wc*64;
  float bv[4];
  #pragma unroll
  for (int n = 0; n < 4; ++n) bv[n] = bias[ccol0 + n*16 + l15];
  #pragma unroll
  for (int m = 0; m < 4; ++m){
    #pragma unroll
    for (int r = 0; r < 4; ++r){
      size_t row = (size_t)(mt*128 + wr*64 + m*16 + lg*4 + r);
      unsigned short* cp = C + row*1024 + ccol0;
      #pragma unroll
      for (int n = 0; n < 4; ++n)
        cp[n*16 + l15] = f2bf(acc[m][n][r] + bv[n]);
    }
  }
}

// one block per (b*16+h, chunk). 256 threads = 4 waves; wave w owns slots [16w,16w+16).
__global__ __launch_bounds__(256) void attn_kernel(
    const unsigned short* __restrict__ Q,
    const unsigned short* __restrict__ K,
    const unsigned short* __restrict__ V,
    float* __restrict__ P)
{
  __shared__ unsigned short Qs[64*64];   // [slot][c], swizzled
  __shared__ unsigned short Ks[64*64];   // [tok][c], swizzled
  __shared__ unsigned short Vt[80*64];   // [c'][tok]; row 64 = ones, 65..79 = 0
  __shared__ unsigned short Al[64*64];   // a[slot][tok] bf16, swizzled
  __shared__ float red[256];             // per-wave column partial sums

  const int bh = blockIdx.x;
  const int chunk = blockIdx.y;
  const int bb = bh >> 4, h = bh & 15;
  const int tid = threadIdx.x;
  const int lane = tid & 63, w = tid >> 6;
  const int l15 = lane & 15, lg = lane >> 4;
  const int lrow = lane >> 3, lch = (lane & 7) << 4;

  // ones/zeros rows of Vt (swizzle-invariant: constant per row)
  for (int i = tid; i < 16*64; i += 256){
    int r = i >> 6;
    Vt[(64 + r)*64 + (i & 63)] = (r == 0) ? (unsigned short)0x3F80 : (unsigned short)0;
  }

  // stage Q head tile (64 slots x 64 c)
  #pragma unroll
  for (int j = 0; j < 2; ++j){
    int row = w*16 + j*8 + lrow;          // slot
    int sw = lch ^ ((row & 7) << 4);
    const char* g = (const char*)Q + (size_t)(row*BATCH + bb)*2048 + h*128 + sw;
    gll16(g, (char*)Qs + (w*16 + j*8)*128);
  }

  const f32x4 fz = {0.f, 0.f, 0.f, 0.f};
  f32x4 acc[5];
  #pragma unroll
  for (int nb = 0; nb < 5; ++nb) acc[nb] = fz;

  const int vtok = tid >> 2;   // 0..63
  const int vcg  = tid & 3;    // 16-channel group
  const int t0 = chunk * CHTOK;

  for (int tt = 0; tt < CHTOK/64; ++tt){
    const int tb = t0 + tt*64;
    // stage K tile
    #pragma unroll
    for (int j = 0; j < 2; ++j){
      int row = w*16 + j*8 + lrow;        // local token
      int sw = lch ^ ((row & 7) << 4);
      const char* g = (const char*)K + (size_t)((size_t)(tb + row)*BATCH + bb)*2048 + h*128 + sw;
      gll16(g, (char*)Ks + (w*16 + j*8)*128);
    }
    // V tile -> regs (coalesced)
    const char* vg = (const char*)V + (size_t)((size_t)(tb + vtok)*BATCH + bb)*2048 + h*128 + vcg*32;
    u16x8 v0 = *(const u16x8*)vg;
    u16x8 v1 = *(const u16x8*)(vg + 16);
    __syncthreads();                      // K (and Q first iter) in LDS; V regs ready

    // S = Q @ K^T for this wave's 16 slot rows; exp in-register
    bf16x8 qa[2];
    #pragma unroll
    for (int kk = 0; kk < 2; ++kk){
      int row = w*16 + l15;
      qa[kk] = *(const bf16x8*)((const char*)Qs + row*128 + ((lg*16 + kk*64) ^ ((row & 7) << 4)));
    }
    float e[4][4];
    #pragma unroll
    for (int nb = 0; nb < 4; ++nb){
      f32x4 s = fz;
      #pragma unroll
      for (int kk = 0; kk < 2; ++kk){
        int row = nb*16 + l15;            // token
        bf16x8 kb = *(const bf16x8*)((const char*)Ks + row*128 + ((lg*16 + kk*64) ^ ((row & 7) << 4)));
        s = __builtin_amdgcn_mfma_f32_16x16x32_bf16(qa[kk], kb, s, 0, 0, 0);
      }
      #pragma unroll
      for (int r = 0; r < 4; ++r) e[nb][r] = __expf(s[r] * 0.125f);
    }
    // per-column (token) partial sums over this wave's 16 slots
    #pragma unroll
    for (int nb = 0; nb < 4; ++nb){
      float cp = e[nb][0] + e[nb][1] + e[nb][2] + e[nb][3];
      cp += __shfl_xor(cp, 16);
      cp += __shfl_xor(cp, 32);
      if (lg == 0) red[w*64 + nb*16 + l15] = cp;
    }
    __syncthreads();                      // red ready; prev-tile PV done 2 barriers ago

    // denominators and normalized a -> Al (bf16, swizzled)
    #pragma unroll
    for (int nb = 0; nb < 4; ++nb){
      int col = nb*16 + l15;
      float dn = red[col] + red[64 + col] + red[128 + col] + red[192 + col];
      float inv = 1.0f / dn;
      #pragma unroll
      for (int r = 0; r < 4; ++r){
        int row = w*16 + lg*4 + r;
        Al[row*64 + ((((2*col)) ^ ((row & 7) << 4)) >> 1)] = f2bf(e[nb][r] * inv);
      }
    }
    // transpose V into Vt (swizzle mixes c>>3 so the 4 cg groups hit distinct banks)
    #pragma unroll
    for (int ee = 0; ee < 8; ++ee){
      int c0 = vcg*16 + ee;
      int sw0 = (((c0 & 7) ^ (c0 >> 3)) & 7) << 4;
      Vt[c0*64 + (((2*vtok) ^ sw0) >> 1)] = v0[ee];
    }
    #pragma unroll
    for (int ee = 0; ee < 8; ++ee){
      int c1 = vcg*16 + 8 + ee;
      int sw1 = (((c1 & 7) ^ (c1 >> 3)) & 7) << 4;
      Vt[c1*64 + (((2*vtok) ^ sw1) >> 1)] = v1[ee];
    }
    __syncthreads();                      // Al, Vt ready

    // PV: acc += a @ [V | 1 | 0...]
    bf16x8 aa[2];
    #pragma unroll
    for (int kk = 0; kk < 2; ++kk){
      int row = w*16 + l15;
      aa[kk] = *(const bf16x8*)((const char*)Al + row*128 + ((lg*16 + kk*64) ^ ((row & 7) << 4)));
    }
    #pragma unroll
    for (int nb = 0; nb < 5; ++nb){
      #pragma unroll
      for (int kk = 0; kk < 2; ++kk){
        int row = nb*16 + l15;            // Vt row = output col
        int sw = (((row & 7) ^ (row >> 3)) & 7) << 4;
        bf16x8 vb = *(const bf16x8*)((const char*)Vt + row*128 + ((lg*16 + kk*64) ^ sw));
        acc[nb] = __builtin_amdgcn_mfma_f32_16x16x32_bf16(aa[kk], vb, acc[nb], 0, 0, 0);
      }
    }
  }

  // write partials: P[bh][chunk][slot][80]  (col 64 = n partial)
  float* Pb = P + (size_t)(bh*NCHUNK + chunk) * 64 * 80;
  #pragma unroll
  for (int nb = 0; nb < 5; ++nb){
    #pragma unroll
    for (int r = 0; r < 4; ++r){
      int s = w*16 + lg*4 + r;
      Pb[(size_t)s*80 + nb*16 + l15] = acc[nb][r];
    }
  }
}

__global__ void reduce_out(const float* __restrict__ P, float* __restrict__ out){
  int flat = blockIdx.x * 256 + threadIdx.x;   // 128*64*64 total
  int c = flat & 63, s = (flat >> 6) & 63, bh = flat >> 12;
  int bb = bh >> 4, h = bh & 15;
  float sc = 0.f, sn = 0.f;
  #pragma unroll
  for (int ch = 0; ch < NCHUNK; ++ch){
    const float* base = P + ((size_t)(bh*NCHUNK + ch)*64 + s)*80;
    sc += base[c];
    sn += base[64];
  }
  out[((size_t)s*BATCH + bb)*1024 + h*64 + c] = sc / (sn + 0.001f);
}

extern "C" void kernel_launch(void* const* d_in, const int* in_sizes, int n_in,
                              void* d_out, int out_size, void* d_ws, size_t ws_size,
                              hipStream_t stream)
{
  const float* s  = (const float*)d_in[0];
  const float* d  = (const float*)d_in[1];
  const float* Wq = (const float*)d_in[2];
  const float* bq = (const float*)d_in[3];
  const float* Wk = (const float*)d_in[4];
  const float* bk = (const float*)d_in[5];
  const float* Wv = (const float*)d_in[6];
  const float* bv = (const float*)d_in[7];
  float* out = (float*)d_out;

  // workspace layout (230,686,720 bytes total)
  char* ws = (char*)d_ws;
  unsigned short* dbf = (unsigned short*)(ws);               // 67,108,864
  unsigned short* sbf = (unsigned short*)(ws + 67108864);    //  1,048,576
  unsigned short* wqb = (unsigned short*)(ws + 68157440);    //  2,097,152
  unsigned short* wkb = (unsigned short*)(ws + 70254592);    //  2,097,152
  unsigned short* wvb = (unsigned short*)(ws + 72351744);    //  2,097,152
  unsigned short* Qw  = (unsigned short*)(ws + 74448896);    //  1,048,576
  unsigned short* Kw  = (unsigned short*)(ws + 75497472);    // 67,108,864
  unsigned short* Vw  = (unsigned short*)(ws + 142606336);   // 67,108,864
  float*          Pw  = (float*)(ws + 209715200);            // 20,971,520

  (void)in_sizes; (void)n_in; (void)out_size; (void)ws_size;

  cvt_bf16<<<(MD*HC/4 + 255)/256, 256, 0, stream>>>(d,  dbf, MD*HC/4);
  cvt_bf16<<<(MS*HC/4 + 255)/256, 256, 0, stream>>>(s,  sbf, MS*HC/4);
  cvt_bf16<<<(HC*HC/4 + 255)/256, 256, 0, stream>>>(Wq, wqb, HC*HC/4);
  cvt_bf16<<<(HC*HC/4 + 255)/256, 256, 0, stream>>>(Wk, wkb, HC*HC/4);
  cvt_bf16<<<(HC*HC/4 + 255)/256, 256, 0, stream>>>(Wv, wvb, HC*HC/4);

  gemm128<<<(MS/128)*8, 256, 0, stream>>>(sbf, wqb, bq, Qw);
  gemm128<<<(MD/128)*8, 256, 0, stream>>>(dbf, wkb, bk, Kw);
  gemm128<<<(MD/128)*8, 256, 0, stream>>>(dbf, wvb, bv, Vw);

  attn_kernel<<<dim3(128, NCHUNK), 256, 0, stream>>>(Qw, Kw, Vw, Pw);

  reduce_out<<<(TS*BATCH*HC)/256, 256, 0, stream>>>(Pw, out);
}

// Round 2
// 255.977 us; speedup vs baseline: 1.0646x; 1.0646x over previous
//
#include <hip/hip_runtime.h>

// SlotAttention on MI355X (gfx950).
// R1: fused K|V GEMM (N=2048) with 256x256 tile, BK=32, 4-slot LDS ring,
// counted-vmcnt deep pipeline (T3+T4), setprio (T5), XOR-swizzled LDS (T2),
// XCD-aware block swizzle (T1). Q GEMM keeps the verified 128^2 kernel.

#define TS 64
#define TD 4096
#define BATCH 8
#define HC 1024
#define NHEAD 16
#define MD (TD*BATCH)   // 32768
#define MS (TS*BATCH)   // 512
#define NCHUNK 8
#define CHTOK (TD/NCHUNK) // 512

#define KTILES 32       // K=1024 / BK=32

typedef __attribute__((ext_vector_type(8))) __bf16 bf16x8;
typedef __attribute__((ext_vector_type(4))) float f32x4;
typedef __attribute__((ext_vector_type(4))) unsigned short u16x4;
typedef __attribute__((ext_vector_type(8))) unsigned short u16x8;

__device__ __forceinline__ unsigned short f2bf(float x){
  union { float f; unsigned u; } v; v.f = x;
  unsigned r = v.u + 0x7FFFu + ((v.u >> 16) & 1u);
  return (unsigned short)(r >> 16);
}

__device__ __forceinline__ void gll16(const void* g, void* l){
  __builtin_amdgcn_global_load_lds((__attribute__((address_space(1))) void*)g,
                                   (__attribute__((address_space(3))) void*)l, 16, 0, 0);
}

__global__ void cvt_bf16(const float* __restrict__ in, unsigned short* __restrict__ out, int n4){
  int i = blockIdx.x * blockDim.x + threadIdx.x;
  if (i >= n4) return;
  f32x4 f = ((const f32x4*)in)[i];
  u16x4 o;
  o[0] = f2bf(f[0]); o[1] = f2bf(f[1]); o[2] = f2bf(f[2]); o[3] = f2bf(f[3]);
  ((u16x4*)out)[i] = o;
}

// ---------------------------------------------------------------------------
// Fused K|V GEMM: C[32768 x 2048] = A @ [Wk;Wv]^T + [bk;bv], bf16 in/out.
// 256x256 tile, BK=32, 8 waves (2Mx4N), per-wave output 128x64.
// LDS: 4-slot ring of (A 16KB + B 16KB) = 128 KiB, tile t -> slot t&3.
// Staging runs 3 tiles ahead: tile t+3's slot == tile t-1's slot, whose reads
// finished before the previous boundary barrier -> WAR-race-free.
// Boundary: s_waitcnt vmcnt(8) (tiles t+2,t+3 in flight) + s_barrier.
// ---------------------------------------------------------------------------
__global__ __launch_bounds__(512, 2) void gemm_kv(
    const unsigned short* __restrict__ A,     // [32768][1024]
    const unsigned short* __restrict__ W,     // [2048][1024] = Wk rows then Wv rows
    const float* __restrict__ bk,
    const float* __restrict__ bv,
    unsigned short* __restrict__ Kout,
    unsigned short* __restrict__ Vout)
{
  __shared__ unsigned short As[4][256*32];
  __shared__ unsigned short Bs[4][256*32];

  const int nwg = gridDim.x;                 // 1024 (multiple of 8)
  const int cpx = nwg >> 3;
  const int orig = blockIdx.x;
  const int wg = (orig & 7) * cpx + (orig >> 3);   // bijective XCD swizzle
  const int mt = wg >> 3, nt = wg & 7;
  const int tid = threadIdx.x;
  const int lane = tid & 63, w = tid >> 6;   // 8 waves
  const int l15 = lane & 15, lg = lane >> 4;
  const int wm = w >> 2, wn = w & 3;

  // ---- staging addressing (pre-swizzled global source, linear LDS dest) ----
  // round j covers tile rows j*128 + w*16 + (lane>>2), chunk (lane&3)*16B
  const int lr = lane >> 2;
  const int schunk = (((lane & 3) ^ ((lane >> 3) & 3)) << 4);
  const char* pa[2]; const char* pb[2]; unsigned ldso[2];
  #pragma unroll
  for (int j = 0; j < 2; ++j){
    int grow = j*128 + w*16 + lr;
    pa[j] = (const char*)A + (size_t)(mt*256 + grow)*2048 + schunk;
    pb[j] = (const char*)W + (size_t)(nt*256 + grow)*2048 + schunk;
    ldso[j] = (unsigned)(j*8192 + w*1024);   // wave-uniform; HW adds lane*16
  }

  #define STAGE_A(t) { char* d = (char*)&As[(t)&3][0]; \
    gll16(pa[0] + (size_t)(t)*64, d + ldso[0]); \
    gll16(pa[1] + (size_t)(t)*64, d + ldso[1]); }
  #define STAGE_B(t) { char* d = (char*)&Bs[(t)&3][0]; \
    gll16(pb[0] + (size_t)(t)*64, d + ldso[0]); \
    gll16(pb[1] + (size_t)(t)*64, d + ldso[1]); }

  // ---- fragment read offsets (swizzle: chunk = lg ^ ((row>>1)&3)) ----
  const unsigned cswz = ((unsigned)(lg ^ ((l15 >> 1) & 3))) << 4;
  const unsigned aoff = (unsigned)(wm*128 + l15)*64 + cswz;   // + mf*1024
  const unsigned boff = (unsigned)(wn*64  + l15)*64 + cswz;   // + nf*1024

  const f32x4 fz = {0.f, 0.f, 0.f, 0.f};
  f32x4 acc[8][4];
  #pragma unroll
  for (int m = 0; m < 8; ++m)
    #pragma unroll
    for (int n = 0; n < 4; ++n) acc[m][n] = fz;

  // ---- prologue: stage tiles 0,1,2; wait tile 0 (8 loads allowed in flight)
  STAGE_A(0) STAGE_B(0) STAGE_A(1) STAGE_B(1) STAGE_A(2) STAGE_B(2)
  asm volatile("s_waitcnt vmcnt(8)" ::: "memory");
  __builtin_amdgcn_s_barrier();
  __builtin_amdgcn_sched_barrier(0);

  for (int t = 0; t < KTILES; ++t){
    const char* as = (const char*)&As[t & 3][0];
    const char* bs = (const char*)&Bs[t & 3][0];

    // ---- phase A: 8 ds_reads + stage-A(t+3) | barrier | 16 MFMA | barrier
    bf16x8 af0[4], bfr[4];
    #pragma unroll
    for (int mf = 0; mf < 4; ++mf) af0[mf] = *(const bf16x8*)(as + aoff + mf*1024u);
    #pragma unroll
    for (int nf = 0; nf < 4; ++nf) bfr[nf] = *(const bf16x8*)(bs + boff + nf*1024u);
    if (t + 3 < KTILES) STAGE_A(t + 3)
    __builtin_amdgcn_s_barrier();
    __builtin_amdgcn_sched_barrier(0);
    __builtin_amdgcn_s_setprio(1);
    #pragma unroll
    for (int mf = 0; mf < 4; ++mf)
      #pragma unroll
      for (int nf = 0; nf < 4; ++nf)
        acc[mf][nf] = __builtin_amdgcn_mfma_f32_16x16x32_bf16(af0[mf], bfr[nf], acc[mf][nf], 0, 0, 0);
    __builtin_amdgcn_s_setprio(0);
    __builtin_amdgcn_s_barrier();

    // ---- phase B: 4 ds_reads + stage-B(t+3) | barrier | 16 MFMA
    bf16x8 af1[4];
    #pragma unroll
    for (int mf = 0; mf < 4; ++mf) af1[mf] = *(const bf16x8*)(as + aoff + (4 + mf)*1024u);
    if (t + 3 < KTILES) STAGE_B(t + 3)
    __builtin_amdgcn_s_barrier();
    __builtin_amdgcn_sched_barrier(0);
    __builtin_amdgcn_s_setprio(1);
    #pragma unroll
    for (int mf = 0; mf < 4; ++mf)
      #pragma unroll
      for (int nf = 0; nf < 4; ++nf)
        acc[4 + mf][nf] = __builtin_amdgcn_mfma_f32_16x16x32_bf16(af1[mf], bfr[nf], acc[4 + mf][nf], 0, 0, 0);
    __builtin_amdgcn_s_setprio(0);

    // ---- tile boundary: counted vmcnt (never 0 until drain) + barrier
    __builtin_amdgcn_sched_barrier(0);
    if (t < KTILES - 3)       { asm volatile("s_waitcnt vmcnt(8)" ::: "memory"); }
    else if (t == KTILES - 3) { asm volatile("s_waitcnt vmcnt(4)" ::: "memory"); }
    else if (t == KTILES - 2) { asm volatile("s_waitcnt vmcnt(0)" ::: "memory"); }
    __builtin_amdgcn_s_barrier();
    __builtin_amdgcn_sched_barrier(0);
  }

  // ---- epilogue: bias + bf16 store. Block's 256 output cols are uniformly
  // in K (nt<4) or V (nt>=4).
  const int ccol = (nt & 3)*256 + wn*64;
  unsigned short* Cb = (nt < 4) ? Kout : Vout;
  const float* bias = (nt < 4) ? bk : bv;
  float bvv[4];
  #pragma unroll
  for (int nf = 0; nf < 4; ++nf) bvv[nf] = bias[ccol + nf*16 + l15];
  #pragma unroll
  for (int mf = 0; mf < 8; ++mf){
    #pragma unroll
    for (int r = 0; r < 4; ++r){
      size_t row = (size_t)(mt*256 + wm*128 + mf*16 + lg*4 + r);
      unsigned short* cp = Cb + row*1024 + ccol;
      #pragma unroll
      for (int nf = 0; nf < 4; ++nf)
        cp[nf*16 + l15] = f2bf(acc[mf][nf][r] + bvv[nf]);
    }
  }
  #undef STAGE_A
  #undef STAGE_B
}

// ---------------------------------------------------------------------------
// 128^2 GEMM kept for Q (M=512): verified in R0.
// ---------------------------------------------------------------------------
__global__ __launch_bounds__(256) void gemm128(
    const unsigned short* __restrict__ A,
    const unsigned short* __restrict__ W,
    const float* __restrict__ bias,
    unsigned short* __restrict__ C)
{
  __shared__ unsigned short As[128*64];
  __shared__ unsigned short Bs[128*64];
  const int nwg = gridDim.x;
  const int cpx = nwg >> 3;
  const int orig = blockIdx.x;
  const int wg = (orig & 7) * cpx + (orig >> 3);
  const int mt = wg >> 3, nt = wg & 7;
  const int tid = threadIdx.x;
  const int lane = tid & 63, w = tid >> 6;
  const int l15 = lane & 15, lg = lane >> 4;
  const int wr = w >> 1, wc = w & 1;

  const int lrow = lane >> 3;
  const int lch  = (lane & 7) << 4;
  const char* pA[4]; const char* pB[4]; unsigned ldsoff[4];
  #pragma unroll
  for (int j = 0; j < 4; ++j){
    int row = w*32 + j*8 + lrow;
    int sw  = lch ^ ((row & 7) << 4);
    pA[j] = (const char*)A + (size_t)(mt*128 + row) * 2048 + sw;
    pB[j] = (const char*)W + (size_t)(nt*128 + row) * 2048 + sw;
    ldsoff[j] = (unsigned)(w*32 + j*8) * 128;
  }

  const f32x4 fz = {0.f, 0.f, 0.f, 0.f};
  f32x4 acc[4][4];
  #pragma unroll
  for (int m = 0; m < 4; ++m)
    #pragma unroll
    for (int n = 0; n < 4; ++n) acc[m][n] = fz;

  for (int kt = 0; kt < 16; ++kt){
    __syncthreads();
    #pragma unroll
    for (int j = 0; j < 4; ++j){
      gll16(pA[j] + (size_t)kt*128, (char*)As + ldsoff[j]);
      gll16(pB[j] + (size_t)kt*128, (char*)Bs + ldsoff[j]);
    }
    __syncthreads();
    #pragma unroll
    for (int kk = 0; kk < 2; ++kk){
      bf16x8 af[4], bfr[4];
      #pragma unroll
      for (int m = 0; m < 4; ++m){
        int row = wr*64 + m*16 + l15;
        af[m] = *(const bf16x8*)((const char*)As + row*128 + ((lg*16 + kk*64) ^ ((row & 7) << 4)));
      }
      #pragma unroll
      for (int n = 0; n < 4; ++n){
        int row = wc*64 + n*16 + l15;
        bfr[n] = *(const bf16x8*)((const char*)Bs + row*128 + ((lg*16 + kk*64) ^ ((row & 7) << 4)));
      }
      #pragma unroll
      for (int m = 0; m < 4; ++m)
        #pragma unroll
        for (int n = 0; n < 4; ++n)
          acc[m][n] = __builtin_amdgcn_mfma_f32_16x16x32_bf16(af[m], bfr[n], acc[m][n], 0, 0, 0);
    }
  }

  const int ccol0 = nt*128 + wc*64;
  float bv[4];
  #pragma unroll
  for (int n = 0; n < 4; ++n) bv[n] = bias[ccol0 + n*16 + l15];
  #pragma unroll
  for (int m = 0; m < 4; ++m){
    #pragma unroll
    for (int r = 0; r < 4; ++r){
      size_t row = (size_t)(mt*128 + wr*64 + m*16 + lg*4 + r);
      unsigned short* cp = C + row*1024 + ccol0;
      #pragma unroll
      for (int n = 0; n < 4; ++n)
        cp[n*16 + l15] = f2bf(acc[m][n][r] + bv[n]);
    }
  }
}

// one block per (b*16+h, chunk). 256 threads = 4 waves; wave w owns slots [16w,16w+16).
__global__ __launch_bounds__(256) void attn_kernel(
    const unsigned short* __restrict__ Q,
    const unsigned short* __restrict__ K,
    const unsigned short* __restrict__ V,
    float* __restrict__ P)
{
  __shared__ unsigned short Qs[64*64];
  __shared__ unsigned short Ks[64*64];
  __shared__ unsigned short Vt[80*64];
  __shared__ unsigned short Al[64*64];
  __shared__ float red[256];

  const int bh = blockIdx.x;
  const int chunk = blockIdx.y;
  const int bb = bh >> 4, h = bh & 15;
  const int tid = threadIdx.x;
  const int lane = tid & 63, w = tid >> 6;
  const int l15 = lane & 15, lg = lane >> 4;
  const int lrow = lane >> 3, lch = (lane & 7) << 4;

  for (int i = tid; i < 16*64; i += 256){
    int r = i >> 6;
    Vt[(64 + r)*64 + (i & 63)] = (r == 0) ? (unsigned short)0x3F80 : (unsigned short)0;
  }

  #pragma unroll
  for (int j = 0; j < 2; ++j){
    int row = w*16 + j*8 + lrow;
    int sw = lch ^ ((row & 7) << 4);
    const char* g = (const char*)Q + (size_t)(row*BATCH + bb)*2048 + h*128 + sw;
    gll16(g, (char*)Qs + (w*16 + j*8)*128);
  }

  const f32x4 fz = {0.f, 0.f, 0.f, 0.f};
  f32x4 acc[5];
  #pragma unroll
  for (int nb = 0; nb < 5; ++nb) acc[nb] = fz;

  const int vtok = tid >> 2;
  const int vcg  = tid & 3;
  const int t0 = chunk * CHTOK;

  for (int tt = 0; tt < CHTOK/64; ++tt){
    const int tb = t0 + tt*64;
    #pragma unroll
    for (int j = 0; j < 2; ++j){
      int row = w*16 + j*8 + lrow;
      int sw = lch ^ ((row & 7) << 4);
      const char* g = (const char*)K + (size_t)((size_t)(tb + row)*BATCH + bb)*2048 + h*128 + sw;
      gll16(g, (char*)Ks + (w*16 + j*8)*128);
    }
    const char* vg = (const char*)V + (size_t)((size_t)(tb + vtok)*BATCH + bb)*2048 + h*128 + vcg*32;
    u16x8 v0 = *(const u16x8*)vg;
    u16x8 v1 = *(const u16x8*)(vg + 16);
    __syncthreads();

    bf16x8 qa[2];
    #pragma unroll
    for (int kk = 0; kk < 2; ++kk){
      int row = w*16 + l15;
      qa[kk] = *(const bf16x8*)((const char*)Qs + row*128 + ((lg*16 + kk*64) ^ ((row & 7) << 4)));
    }
    float e[4][4];
    #pragma unroll
    for (int nb = 0; nb < 4; ++nb){
      f32x4 s = fz;
      #pragma unroll
      for (int kk = 0; kk < 2; ++kk){
        int row = nb*16 + l15;
        bf16x8 kb = *(const bf16x8*)((const char*)Ks + row*128 + ((lg*16 + kk*64) ^ ((row & 7) << 4)));
        s = __builtin_amdgcn_mfma_f32_16x16x32_bf16(qa[kk], kb, s, 0, 0, 0);
      }
      #pragma unroll
      for (int r = 0; r < 4; ++r) e[nb][r] = __expf(s[r] * 0.125f);
    }
    #pragma unroll
    for (int nb = 0; nb < 4; ++nb){
      float cp = e[nb][0] + e[nb][1] + e[nb][2] + e[nb][3];
      cp += __shfl_xor(cp, 16);
      cp += __shfl_xor(cp, 32);
      if (lg == 0) red[w*64 + nb*16 + l15] = cp;
    }
    __syncthreads();

    #pragma unroll
    for (int nb = 0; nb < 4; ++nb){
      int col = nb*16 + l15;
      float dn = red[col] + red[64 + col] + red[128 + col] + red[192 + col];
      float inv = 1.0f / dn;
      #pragma unroll
      for (int r = 0; r < 4; ++r){
        int row = w*16 + lg*4 + r;
        Al[row*64 + ((((2*col)) ^ ((row & 7) << 4)) >> 1)] = f2bf(e[nb][r] * inv);
      }
    }
    #pragma unroll
    for (int ee = 0; ee < 8; ++ee){
      int c0 = vcg*16 + ee;
      int sw0 = (((c0 & 7) ^ (c0 >> 3)) & 7) << 4;
      Vt[c0*64 + (((2*vtok) ^ sw0) >> 1)] = v0[ee];
    }
    #pragma unroll
    for (int ee = 0; ee < 8; ++ee){
      int c1 = vcg*16 + 8 + ee;
      int sw1 = (((c1 & 7) ^ (c1 >> 3)) & 7) << 4;
      Vt[c1*64 + (((2*vtok) ^ sw1) >> 1)] = v1[ee];
    }
    __syncthreads();

    bf16x8 aa[2];
    #pragma unroll
    for (int kk = 0; kk < 2; ++kk){
      int row = w*16 + l15;
      aa[kk] = *(const bf16x8*)((const char*)Al + row*128 + ((lg*16 + kk*64) ^ ((row & 7) << 4)));
    }
    #pragma unroll
    for (int nb = 0; nb < 5; ++nb){
      #pragma unroll
      for (int kk = 0; kk < 2; ++kk){
        int row = nb*16 + l15;
        int sw = (((row & 7) ^ (row >> 3)) & 7) << 4;
        bf16x8 vb = *(const bf16x8*)((const char*)Vt + row*128 + ((lg*16 + kk*64) ^ sw));
        acc[nb] = __builtin_amdgcn_mfma_f32_16x16x32_bf16(aa[kk], vb, acc[nb], 0, 0, 0);
      }
    }
  }

  float* Pb = P + (size_t)(bh*NCHUNK + chunk) * 64 * 80;
  #pragma unroll
  for (int nb = 0; nb < 5; ++nb){
    #pragma unroll
    for (int r = 0; r < 4; ++r){
      int s = w*16 + lg*4 + r;
      Pb[(size_t)s*80 + nb*16 + l15] = acc[nb][r];
    }
  }
}

__global__ void reduce_out(const float* __restrict__ P, float* __restrict__ out){
  int flat = blockIdx.x * 256 + threadIdx.x;
  int c = flat & 63, s = (flat >> 6) & 63, bh = flat >> 12;
  int bb = bh >> 4, h = bh & 15;
  float sc = 0.f, sn = 0.f;
  #pragma unroll
  for (int ch = 0; ch < NCHUNK; ++ch){
    const float* base = P + ((size_t)(bh*NCHUNK + ch)*64 + s)*80;
    sc += base[c];
    sn += base[64];
  }
  out[((size_t)s*BATCH + bb)*1024 + h*64 + c] = sc / (sn + 0.001f);
}

extern "C" void kernel_launch(void* const* d_in, const int* in_sizes, int n_in,
                              void* d_out, int out_size, void* d_ws, size_t ws_size,
                              hipStream_t stream)
{
  const float* s  = (const float*)d_in[0];
  const float* d  = (const float*)d_in[1];
  const float* Wq = (const float*)d_in[2];
  const float* bq = (const float*)d_in[3];
  const float* Wk = (const float*)d_in[4];
  const float* bk = (const float*)d_in[5];
  const float* Wv = (const float*)d_in[6];
  const float* bv = (const float*)d_in[7];
  float* out = (float*)d_out;

  char* ws = (char*)d_ws;
  unsigned short* dbf = (unsigned short*)(ws);               // 67,108,864
  unsigned short* sbf = (unsigned short*)(ws + 67108864);    //  1,048,576
  unsigned short* wqb = (unsigned short*)(ws + 68157440);    //  2,097,152
  unsigned short* wkb = (unsigned short*)(ws + 70254592);    //  2,097,152 (Wk rows 0..1023)
  unsigned short* wvb = (unsigned short*)(ws + 72351744);    //  2,097,152 (Wv rows = wkb rows 1024..2047)
  unsigned short* Qw  = (unsigned short*)(ws + 74448896);    //  1,048,576
  unsigned short* Kw  = (unsigned short*)(ws + 75497472);    // 67,108,864
  unsigned short* Vw  = (unsigned short*)(ws + 142606336);   // 67,108,864
  float*          Pw  = (float*)(ws + 209715200);            // 20,971,520

  (void)in_sizes; (void)n_in; (void)out_size; (void)ws_size;

  cvt_bf16<<<(MD*HC/4 + 255)/256, 256, 0, stream>>>(d,  dbf, MD*HC/4);
  cvt_bf16<<<(MS*HC/4 + 255)/256, 256, 0, stream>>>(s,  sbf, MS*HC/4);
  cvt_bf16<<<(HC*HC/4 + 255)/256, 256, 0, stream>>>(Wq, wqb, HC*HC/4);
  cvt_bf16<<<(HC*HC/4 + 255)/256, 256, 0, stream>>>(Wk, wkb, HC*HC/4);
  cvt_bf16<<<(HC*HC/4 + 255)/256, 256, 0, stream>>>(Wv, wvb, HC*HC/4);

  gemm128<<<(MS/128)*8, 256, 0, stream>>>(sbf, wqb, bq, Qw);
  gemm_kv<<<(MD/256)*8, 512, 0, stream>>>(dbf, wkb, bk, bv, Kw, Vw);

  attn_kernel<<<dim3(128, NCHUNK), 256, 0, stream>>>(Qw, Kw, Vw, Pw);

  reduce_out<<<(TS*BATCH*HC)/256, 256, 0, stream>>>(Pw, out);
}

// Round 3
// 254.010 us; speedup vs baseline: 1.0729x; 1.0077x over previous
//
#include <hip/hip_runtime.h>

// SlotAttention on MI355X (gfx950).
// R2: gemm_kv barrier-light schedule — ONE counted-vmcnt + s_barrier per K-tile
// (ring-slot WAR protection only); no intra-tile barriers. Waves free-run so
// ds_read latency hides under the sibling wave's MFMA issue.

#define TS 64
#define TD 4096
#define BATCH 8
#define HC 1024
#define NHEAD 16
#define MD (TD*BATCH)   // 32768
#define MS (TS*BATCH)   // 512
#define NCHUNK 8
#define CHTOK (TD/NCHUNK) // 512

#define KTILES 32       // K=1024 / BK=32

typedef __attribute__((ext_vector_type(8))) __bf16 bf16x8;
typedef __attribute__((ext_vector_type(4))) float f32x4;
typedef __attribute__((ext_vector_type(4))) unsigned short u16x4;
typedef __attribute__((ext_vector_type(8))) unsigned short u16x8;

__device__ __forceinline__ unsigned short f2bf(float x){
  union { float f; unsigned u; } v; v.f = x;
  unsigned r = v.u + 0x7FFFu + ((v.u >> 16) & 1u);
  return (unsigned short)(r >> 16);
}

__device__ __forceinline__ void gll16(const void* g, void* l){
  __builtin_amdgcn_global_load_lds((__attribute__((address_space(1))) void*)g,
                                   (__attribute__((address_space(3))) void*)l, 16, 0, 0);
}

__global__ void cvt_bf16(const float* __restrict__ in, unsigned short* __restrict__ out, int n4){
  int i = blockIdx.x * blockDim.x + threadIdx.x;
  if (i >= n4) return;
  f32x4 f = ((const f32x4*)in)[i];
  u16x4 o;
  o[0] = f2bf(f[0]); o[1] = f2bf(f[1]); o[2] = f2bf(f[2]); o[3] = f2bf(f[3]);
  ((u16x4*)out)[i] = o;
}

// ---------------------------------------------------------------------------
// Fused K|V GEMM: C[32768 x 2048] = A @ [Wk;Wv]^T + [bk;bv], bf16 in/out.
// 256x256 tile, BK=32, 8 waves (2Mx4N), per-wave output 128x64.
// LDS: 4-slot ring of (A 16KB + B 16KB) = 128 KiB, tile t -> slot t&3.
// Staging runs 3 tiles ahead. ONE barrier per tile (slot-WAR protection):
// every ds_read of tile t-1 is consumed by an MFMA before the boundary
// barrier of tile t (compiler lgkm waits), so staging into slot (t+3)&3 ==
// (t-1)&3 after the barrier cannot race pending reads.
// ---------------------------------------------------------------------------
__global__ __launch_bounds__(512, 2) void gemm_kv(
    const unsigned short* __restrict__ A,     // [32768][1024]
    const unsigned short* __restrict__ W,     // [2048][1024] = Wk rows then Wv rows
    const float* __restrict__ bk,
    const float* __restrict__ bv,
    unsigned short* __restrict__ Kout,
    unsigned short* __restrict__ Vout)
{
  __shared__ unsigned short As[4][256*32];
  __shared__ unsigned short Bs[4][256*32];

  const int nwg = gridDim.x;                 // 1024 (multiple of 8)
  const int cpx = nwg >> 3;
  const int orig = blockIdx.x;
  const int wg = (orig & 7) * cpx + (orig >> 3);   // bijective XCD swizzle
  const int mt = wg >> 3, nt = wg & 7;
  const int tid = threadIdx.x;
  const int lane = tid & 63, w = tid >> 6;   // 8 waves
  const int l15 = lane & 15, lg = lane >> 4;
  const int wm = w >> 2, wn = w & 3;

  // ---- staging addressing (pre-swizzled global source, linear LDS dest) ----
  const int lr = lane >> 2;
  const int schunk = (((lane & 3) ^ ((lane >> 3) & 3)) << 4);
  const char* pa[2]; const char* pb[2]; unsigned ldso[2];
  #pragma unroll
  for (int j = 0; j < 2; ++j){
    int grow = j*128 + w*16 + lr;
    pa[j] = (const char*)A + (size_t)(mt*256 + grow)*2048 + schunk;
    pb[j] = (const char*)W + (size_t)(nt*256 + grow)*2048 + schunk;
    ldso[j] = (unsigned)(j*8192 + w*1024);   // wave-uniform; HW adds lane*16
  }

  #define STAGE_A(t) { char* dst = (char*)&As[(t)&3][0]; \
    gll16(pa[0] + (size_t)(t)*64, dst + ldso[0]); \
    gll16(pa[1] + (size_t)(t)*64, dst + ldso[1]); }
  #define STAGE_B(t) { char* dst = (char*)&Bs[(t)&3][0]; \
    gll16(pb[0] + (size_t)(t)*64, dst + ldso[0]); \
    gll16(pb[1] + (size_t)(t)*64, dst + ldso[1]); }

  // ---- fragment read offsets (swizzle: chunk = lg ^ ((row>>1)&3)) ----
  const unsigned cswz = ((unsigned)(lg ^ ((l15 >> 1) & 3))) << 4;
  const unsigned aoff = (unsigned)(wm*128 + l15)*64 + cswz;   // + mf*1024
  const unsigned boff = (unsigned)(wn*64  + l15)*64 + cswz;   // + nf*1024

  const f32x4 fz = {0.f, 0.f, 0.f, 0.f};
  f32x4 acc[8][4];
  #pragma unroll
  for (int m = 0; m < 8; ++m)
    #pragma unroll
    for (int n = 0; n < 4; ++n) acc[m][n] = fz;

  // ---- prologue: stage tiles 0,1,2; wait tile 0 (8 loads still in flight)
  STAGE_A(0) STAGE_B(0) STAGE_A(1) STAGE_B(1) STAGE_A(2) STAGE_B(2)
  asm volatile("s_waitcnt vmcnt(8)" ::: "memory");
  __builtin_amdgcn_s_barrier();
  __builtin_amdgcn_sched_barrier(0);

  for (int t = 0; t < KTILES; ++t){
    const char* as = (const char*)&As[t & 3][0];
    const char* bs = (const char*)&Bs[t & 3][0];

    // ---- half 1: reads + stage-A(t+3), 16 MFMA (no barriers; waves drift)
    bf16x8 af0[4], bfr[4];
    #pragma unroll
    for (int mf = 0; mf < 4; ++mf) af0[mf] = *(const bf16x8*)(as + aoff + mf*1024u);
    #pragma unroll
    for (int nf = 0; nf < 4; ++nf) bfr[nf] = *(const bf16x8*)(bs + boff + nf*1024u);
    if (t + 3 < KTILES) STAGE_A(t + 3)
    __builtin_amdgcn_s_setprio(1);
    #pragma unroll
    for (int mf = 0; mf < 4; ++mf)
      #pragma unroll
      for (int nf = 0; nf < 4; ++nf)
        acc[mf][nf] = __builtin_amdgcn_mfma_f32_16x16x32_bf16(af0[mf], bfr[nf], acc[mf][nf], 0, 0, 0);
    __builtin_amdgcn_s_setprio(0);

    // ---- half 2: reads + stage-B(t+3), 16 MFMA
    bf16x8 af1[4];
    #pragma unroll
    for (int mf = 0; mf < 4; ++mf) af1[mf] = *(const bf16x8*)(as + aoff + (4 + mf)*1024u);
    if (t + 3 < KTILES) STAGE_B(t + 3)
    __builtin_amdgcn_s_setprio(1);
    #pragma unroll
    for (int mf = 0; mf < 4; ++mf)
      #pragma unroll
      for (int nf = 0; nf < 4; ++nf)
        acc[4 + mf][nf] = __builtin_amdgcn_mfma_f32_16x16x32_bf16(af1[mf], bfr[nf], acc[4 + mf][nf], 0, 0, 0);
    __builtin_amdgcn_s_setprio(0);

    // ---- tile boundary: counted vmcnt (never 0 until drain) + ONE barrier
    __builtin_amdgcn_sched_barrier(0);
    if (t < KTILES - 3)       { asm volatile("s_waitcnt vmcnt(8)" ::: "memory"); }
    else if (t == KTILES - 3) { asm volatile("s_waitcnt vmcnt(4)" ::: "memory"); }
    else if (t == KTILES - 2) { asm volatile("s_waitcnt vmcnt(0)" ::: "memory"); }
    __builtin_amdgcn_s_barrier();
    __builtin_amdgcn_sched_barrier(0);
  }

  // ---- epilogue: bias + bf16 store (block's 256 cols uniformly K or V)
  const int ccol = (nt & 3)*256 + wn*64;
  unsigned short* Cb = (nt < 4) ? Kout : Vout;
  const float* bias = (nt < 4) ? bk : bv;
  float bvv[4];
  #pragma unroll
  for (int nf = 0; nf < 4; ++nf) bvv[nf] = bias[ccol + nf*16 + l15];
  #pragma unroll
  for (int mf = 0; mf < 8; ++mf){
    #pragma unroll
    for (int r = 0; r < 4; ++r){
      size_t row = (size_t)(mt*256 + wm*128 + mf*16 + lg*4 + r);
      unsigned short* cp = Cb + row*1024 + ccol;
      #pragma unroll
      for (int nf = 0; nf < 4; ++nf)
        cp[nf*16 + l15] = f2bf(acc[mf][nf][r] + bvv[nf]);
    }
  }
  #undef STAGE_A
  #undef STAGE_B
}

// ---------------------------------------------------------------------------
// 128^2 GEMM kept for Q (M=512): verified in R0.
// ---------------------------------------------------------------------------
__global__ __launch_bounds__(256) void gemm128(
    const unsigned short* __restrict__ A,
    const unsigned short* __restrict__ W,
    const float* __restrict__ bias,
    unsigned short* __restrict__ C)
{
  __shared__ unsigned short As[128*64];
  __shared__ unsigned short Bs[128*64];
  const int nwg = gridDim.x;
  const int cpx = nwg >> 3;
  const int orig = blockIdx.x;
  const int wg = (orig & 7) * cpx + (orig >> 3);
  const int mt = wg >> 3, nt = wg & 7;
  const int tid = threadIdx.x;
  const int lane = tid & 63, w = tid >> 6;
  const int l15 = lane & 15, lg = lane >> 4;
  const int wr = w >> 1, wc = w & 1;

  const int lrow = lane >> 3;
  const int lch  = (lane & 7) << 4;
  const char* pA[4]; const char* pB[4]; unsigned ldsoff[4];
  #pragma unroll
  for (int j = 0; j < 4; ++j){
    int row = w*32 + j*8 + lrow;
    int sw  = lch ^ ((row & 7) << 4);
    pA[j] = (const char*)A + (size_t)(mt*128 + row) * 2048 + sw;
    pB[j] = (const char*)W + (size_t)(nt*128 + row) * 2048 + sw;
    ldsoff[j] = (unsigned)(w*32 + j*8) * 128;
  }

  const f32x4 fz = {0.f, 0.f, 0.f, 0.f};
  f32x4 acc[4][4];
  #pragma unroll
  for (int m = 0; m < 4; ++m)
    #pragma unroll
    for (int n = 0; n < 4; ++n) acc[m][n] = fz;

  for (int kt = 0; kt < 16; ++kt){
    __syncthreads();
    #pragma unroll
    for (int j = 0; j < 4; ++j){
      gll16(pA[j] + (size_t)kt*128, (char*)As + ldsoff[j]);
      gll16(pB[j] + (size_t)kt*128, (char*)Bs + ldsoff[j]);
    }
    __syncthreads();
    #pragma unroll
    for (int kk = 0; kk < 2; ++kk){
      bf16x8 af[4], bfr[4];
      #pragma unroll
      for (int m = 0; m < 4; ++m){
        int row = wr*64 + m*16 + l15;
        af[m] = *(const bf16x8*)((const char*)As + row*128 + ((lg*16 + kk*64) ^ ((row & 7) << 4)));
      }
      #pragma unroll
      for (int n = 0; n < 4; ++n){
        int row = wc*64 + n*16 + l15;
        bfr[n] = *(const bf16x8*)((const char*)Bs + row*128 + ((lg*16 + kk*64) ^ ((row & 7) << 4)));
      }
      #pragma unroll
      for (int m = 0; m < 4; ++m)
        #pragma unroll
        for (int n = 0; n < 4; ++n)
          acc[m][n] = __builtin_amdgcn_mfma_f32_16x16x32_bf16(af[m], bfr[n], acc[m][n], 0, 0, 0);
    }
  }

  const int ccol0 = nt*128 + wc*64;
  float bv[4];
  #pragma unroll
  for (int n = 0; n < 4; ++n) bv[n] = bias[ccol0 + n*16 + l15];
  #pragma unroll
  for (int m = 0; m < 4; ++m){
    #pragma unroll
    for (int r = 0; r < 4; ++r){
      size_t row = (size_t)(mt*128 + wr*64 + m*16 + lg*4 + r);
      unsigned short* cp = C + row*1024 + ccol0;
      #pragma unroll
      for (int n = 0; n < 4; ++n)
        cp[n*16 + l15] = f2bf(acc[m][n][r] + bv[n]);
    }
  }
}

// one block per (b*16+h, chunk). 256 threads = 4 waves; wave w owns slots [16w,16w+16).
__global__ __launch_bounds__(256) void attn_kernel(
    const unsigned short* __restrict__ Q,
    const unsigned short* __restrict__ K,
    const unsigned short* __restrict__ V,
    float* __restrict__ P)
{
  __shared__ unsigned short Qs[64*64];
  __shared__ unsigned short Ks[64*64];
  __shared__ unsigned short Vt[80*64];
  __shared__ unsigned short Al[64*64];
  __shared__ float red[256];

  const int bh = blockIdx.x;
  const int chunk = blockIdx.y;
  const int bb = bh >> 4, h = bh & 15;
  const int tid = threadIdx.x;
  const int lane = tid & 63, w = tid >> 6;
  const int l15 = lane & 15, lg = lane >> 4;
  const int lrow = lane >> 3, lch = (lane & 7) << 4;

  for (int i = tid; i < 16*64; i += 256){
    int r = i >> 6;
    Vt[(64 + r)*64 + (i & 63)] = (r == 0) ? (unsigned short)0x3F80 : (unsigned short)0;
  }

  #pragma unroll
  for (int j = 0; j < 2; ++j){
    int row = w*16 + j*8 + lrow;
    int sw = lch ^ ((row & 7) << 4);
    const char* g = (const char*)Q + (size_t)(row*BATCH + bb)*2048 + h*128 + sw;
    gll16(g, (char*)Qs + (w*16 + j*8)*128);
  }

  const f32x4 fz = {0.f, 0.f, 0.f, 0.f};
  f32x4 acc[5];
  #pragma unroll
  for (int nb = 0; nb < 5; ++nb) acc[nb] = fz;

  const int vtok = tid >> 2;
  const int vcg  = tid & 3;
  const int t0 = chunk * CHTOK;

  for (int tt = 0; tt < CHTOK/64; ++tt){
    const int tb = t0 + tt*64;
    #pragma unroll
    for (int j = 0; j < 2; ++j){
      int row = w*16 + j*8 + lrow;
      int sw = lch ^ ((row & 7) << 4);
      const char* g = (const char*)K + (size_t)((size_t)(tb + row)*BATCH + bb)*2048 + h*128 + sw;
      gll16(g, (char*)Ks + (w*16 + j*8)*128);
    }
    const char* vg = (const char*)V + (size_t)((size_t)(tb + vtok)*BATCH + bb)*2048 + h*128 + vcg*32;
    u16x8 v0 = *(const u16x8*)vg;
    u16x8 v1 = *(const u16x8*)(vg + 16);
    __syncthreads();

    bf16x8 qa[2];
    #pragma unroll
    for (int kk = 0; kk < 2; ++kk){
      int row = w*16 + l15;
      qa[kk] = *(const bf16x8*)((const char*)Qs + row*128 + ((lg*16 + kk*64) ^ ((row & 7) << 4)));
    }
    float e[4][4];
    #pragma unroll
    for (int nb = 0; nb < 4; ++nb){
      f32x4 s = fz;
      #pragma unroll
      for (int kk = 0; kk < 2; ++kk){
        int row = nb*16 + l15;
        bf16x8 kb = *(const bf16x8*)((const char*)Ks + row*128 + ((lg*16 + kk*64) ^ ((row & 7) << 4)));
        s = __builtin_amdgcn_mfma_f32_16x16x32_bf16(qa[kk], kb, s, 0, 0, 0);
      }
      #pragma unroll
      for (int r = 0; r < 4; ++r) e[nb][r] = __expf(s[r] * 0.125f);
    }
    #pragma unroll
    for (int nb = 0; nb < 4; ++nb){
      float cp = e[nb][0] + e[nb][1] + e[nb][2] + e[nb][3];
      cp += __shfl_xor(cp, 16);
      cp += __shfl_xor(cp, 32);
      if (lg == 0) red[w*64 + nb*16 + l15] = cp;
    }
    __syncthreads();

    #pragma unroll
    for (int nb = 0; nb < 4; ++nb){
      int col = nb*16 + l15;
      float dn = red[col] + red[64 + col] + red[128 + col] + red[192 + col];
      float inv = 1.0f / dn;
      #pragma unroll
      for (int r = 0; r < 4; ++r){
        int row = w*16 + lg*4 + r;
        Al[row*64 + ((((2*col)) ^ ((row & 7) << 4)) >> 1)] = f2bf(e[nb][r] * inv);
      }
    }
    #pragma unroll
    for (int ee = 0; ee < 8; ++ee){
      int c0 = vcg*16 + ee;
      int sw0 = (((c0 & 7) ^ (c0 >> 3)) & 7) << 4;
      Vt[c0*64 + (((2*vtok) ^ sw0) >> 1)] = v0[ee];
    }
    #pragma unroll
    for (int ee = 0; ee < 8; ++ee){
      int c1 = vcg*16 + 8 + ee;
      int sw1 = (((c1 & 7) ^ (c1 >> 3)) & 7) << 4;
      Vt[c1*64 + (((2*vtok) ^ sw1) >> 1)] = v1[ee];
    }
    __syncthreads();

    bf16x8 aa[2];
    #pragma unroll
    for (int kk = 0; kk < 2; ++kk){
      int row = w*16 + l15;
      aa[kk] = *(const bf16x8*)((const char*)Al + row*128 + ((lg*16 + kk*64) ^ ((row & 7) << 4)));
    }
    #pragma unroll
    for (int nb = 0; nb < 5; ++nb){
      #pragma unroll
      for (int kk = 0; kk < 2; ++kk){
        int row = nb*16 + l15;
        int sw = (((row & 7) ^ (row >> 3)) & 7) << 4;
        bf16x8 vb = *(const bf16x8*)((const char*)Vt + row*128 + ((lg*16 + kk*64) ^ sw));
        acc[nb] = __builtin_amdgcn_mfma_f32_16x16x32_bf16(aa[kk], vb, acc[nb], 0, 0, 0);
      }
    }
  }

  float* Pb = P + (size_t)(bh*NCHUNK + chunk) * 64 * 80;
  #pragma unroll
  for (int nb = 0; nb < 5; ++nb){
    #pragma unroll
    for (int r = 0; r < 4; ++r){
      int s = w*16 + lg*4 + r;
      Pb[(size_t)s*80 + nb*16 + l15] = acc[nb][r];
    }
  }
}

__global__ void reduce_out(const float* __restrict__ P, float* __restrict__ out){
  int flat = blockIdx.x * 256 + threadIdx.x;
  int c = flat & 63, s = (flat >> 6) & 63, bh = flat >> 12;
  int bb = bh >> 4, h = bh & 15;
  float sc = 0.f, sn = 0.f;
  #pragma unroll
  for (int ch = 0; ch < NCHUNK; ++ch){
    const float* base = P + ((size_t)(bh*NCHUNK + ch)*64 + s)*80;
    sc += base[c];
    sn += base[64];
  }
  out[((size_t)s*BATCH + bb)*1024 + h*64 + c] = sc / (sn + 0.001f);
}

extern "C" void kernel_launch(void* const* d_in, const int* in_sizes, int n_in,
                              void* d_out, int out_size, void* d_ws, size_t ws_size,
                              hipStream_t stream)
{
  const float* s  = (const float*)d_in[0];
  const float* d  = (const float*)d_in[1];
  const float* Wq = (const float*)d_in[2];
  const float* bq = (const float*)d_in[3];
  const float* Wk = (const float*)d_in[4];
  const float* bk = (const float*)d_in[5];
  const float* Wv = (const float*)d_in[6];
  const float* bv = (const float*)d_in[7];
  float* out = (float*)d_out;

  char* ws = (char*)d_ws;
  unsigned short* dbf = (unsigned short*)(ws);               // 67,108,864
  unsigned short* sbf = (unsigned short*)(ws + 67108864);    //  1,048,576
  unsigned short* wqb = (unsigned short*)(ws + 68157440);    //  2,097,152
  unsigned short* wkb = (unsigned short*)(ws + 70254592);    //  2,097,152 (Wk rows 0..1023)
  unsigned short* wvb = (unsigned short*)(ws + 72351744);    //  2,097,152 (Wv rows = wkb rows 1024..2047)
  unsigned short* Qw  = (unsigned short*)(ws + 74448896);    //  1,048,576
  unsigned short* Kw  = (unsigned short*)(ws + 75497472);    // 67,108,864
  unsigned short* Vw  = (unsigned short*)(ws + 142606336);   // 67,108,864
  float*          Pw  = (float*)(ws + 209715200);            // 20,971,520

  (void)in_sizes; (void)n_in; (void)out_size; (void)ws_size;

  cvt_bf16<<<(MD*HC/4 + 255)/256, 256, 0, stream>>>(d,  dbf, MD*HC/4);
  cvt_bf16<<<(MS*HC/4 + 255)/256, 256, 0, stream>>>(s,  sbf, MS*HC/4);
  cvt_bf16<<<(HC*HC/4 + 255)/256, 256, 0, stream>>>(Wq, wqb, HC*HC/4);
  cvt_bf16<<<(HC*HC/4 + 255)/256, 256, 0, stream>>>(Wk, wkb, HC*HC/4);
  cvt_bf16<<<(HC*HC/4 + 255)/256, 256, 0, stream>>>(Wv, wvb, HC*HC/4);

  gemm128<<<(MS/128)*8, 256, 0, stream>>>(sbf, wqb, bq, Qw);
  gemm_kv<<<(MD/256)*8, 512, 0, stream>>>(dbf, wkb, bk, bv, Kw, Vw);

  attn_kernel<<<dim3(128, NCHUNK), 256, 0, stream>>>(Qw, Kw, Vw, Pw);

  reduce_out<<<(TS*BATCH*HC)/256, 256, 0, stream>>>(Pw, out);
}